// Round 5
// baseline (1150.598 us; speedup 1.0000x reference)
//
#include <hip/hip_runtime.h>
#include <stdint.h>

#define T_TOK 8192
#define DM 1024
#define HID 4096
#define NE 8
#define RP2 18432      // 16384 + 8*256 worst-case rows padded to 256
#define MT128 144      // RP2 / 128
#define MT256 72       // RP2 / 256

typedef unsigned short u16;
typedef __attribute__((ext_vector_type(16))) float f32x16;
typedef __attribute__((ext_vector_type(8))) __bf16 bf16x8;

#define GLB(p) ((const __attribute__((address_space(1))) unsigned int*)(p))
#define LDSP(p) ((__attribute__((address_space(3))) unsigned int*)(p))

__device__ __forceinline__ u16 f2bf(float f) {
    union { float f; unsigned u; } c; c.f = f;
    unsigned r = (c.u + 0x7FFFu + ((c.u >> 16) & 1u)) >> 16;
    return (u16)r;
}

template<int Nw> __device__ __forceinline__ void vmwait() {
    if constexpr (Nw == 0)       asm volatile("s_waitcnt vmcnt(0)" ::: "memory");
    else if constexpr (Nw == 4)  asm volatile("s_waitcnt vmcnt(4)" ::: "memory");
    else if constexpr (Nw == 6)  asm volatile("s_waitcnt vmcnt(6)" ::: "memory");
    else if constexpr (Nw == 8)  asm volatile("s_waitcnt vmcnt(8)" ::: "memory");
    else if constexpr (Nw == 12) asm volatile("s_waitcnt vmcnt(12)" ::: "memory");
}

// ---------- 0: zero counters ----------
__global__ void k_zero(int* counts, int* cursors) {
    if (threadIdx.x < NE) { counts[threadIdx.x] = 0; cursors[threadIdx.x] = 0; }
}

// ---------- 1: gating (one wave per token, fp32) ----------
__global__ __launch_bounds__(256) void k_gate(const float* __restrict__ x,
        const float* __restrict__ gw, const float* __restrict__ gb,
        int* __restrict__ tok_e, float* __restrict__ tok_w, int* __restrict__ counts) {
    int t = blockIdx.x * 4 + (threadIdx.x >> 6);
    int lane = threadIdx.x & 63;
    const float* xr = x + (size_t)t * DM;
    float a0=0,a1=0,a2=0,a3=0,a4=0,a5=0,a6=0,a7=0;
    for (int d = lane; d < DM; d += 64) {
        float xv = xr[d];
        const float4* g = (const float4*)(gw + (size_t)d * NE);
        float4 g0 = g[0], g1 = g[1];
        a0 += xv*g0.x; a1 += xv*g0.y; a2 += xv*g0.z; a3 += xv*g0.w;
        a4 += xv*g1.x; a5 += xv*g1.y; a6 += xv*g1.z; a7 += xv*g1.w;
    }
    #pragma unroll
    for (int off = 32; off; off >>= 1) {
        a0 += __shfl_xor(a0, off); a1 += __shfl_xor(a1, off);
        a2 += __shfl_xor(a2, off); a3 += __shfl_xor(a3, off);
        a4 += __shfl_xor(a4, off); a5 += __shfl_xor(a5, off);
        a6 += __shfl_xor(a6, off); a7 += __shfl_xor(a7, off);
    }
    if (lane == 0) {
        float l[8] = {a0+gb[0],a1+gb[1],a2+gb[2],a3+gb[3],a4+gb[4],a5+gb[5],a6+gb[6],a7+gb[7]};
        int e0 = 0;
        #pragma unroll
        for (int e = 1; e < 8; ++e) if (l[e] > l[e0]) e0 = e;
        int e1 = (e0 == 0) ? 1 : 0;
        #pragma unroll
        for (int e = 0; e < 8; ++e) if (e != e0 && l[e] > l[e1]) e1 = e;
        float p1 = expf(l[e1] - l[e0]);
        float inv = 1.f / (1.f + p1);
        tok_e[2*t] = e0; tok_e[2*t+1] = e1;
        tok_w[2*t] = inv; tok_w[2*t+1] = p1 * inv;
        atomicAdd(&counts[e0], 1);
        atomicAdd(&counts[e1], 1);
    }
}

// ---------- 2: padded prefix (256-aligned) + tile->expert map (128-granular) ----------
__global__ void k_scan(const int* __restrict__ counts, int* __restrict__ pad_off,
                       int* __restrict__ tile_expert, int* __restrict__ row_token) {
    __shared__ int off[NE + 1];
    if (threadIdx.x == 0) {
        int o = 0;
        for (int e = 0; e < NE; ++e) { off[e] = o; pad_off[e] = o; o += ((counts[e] + 255) >> 8) << 8; }
        off[NE] = o; pad_off[NE] = o;
    }
    __syncthreads();
    for (int i = threadIdx.x; i < MT128; i += blockDim.x) {
        int ex = -1, base = i * 128;
        #pragma unroll
        for (int e = 0; e < NE; ++e) if (base >= off[e] && base < off[e+1]) ex = e;
        tile_expert[i] = ex;
    }
    for (int i = threadIdx.x; i < RP2; i += blockDim.x) row_token[i] = -1;
}

// ---------- 3: assign rows ----------
__global__ __launch_bounds__(256) void k_assign(const int* __restrict__ tok_e, const float* __restrict__ tok_w,
        const int* __restrict__ pad_off, int* __restrict__ cursors,
        int* __restrict__ row_token, float* __restrict__ row_weight, int* __restrict__ token_rows) {
    int t = blockIdx.x * 256 + threadIdx.x;
    if (t >= T_TOK) return;
    #pragma unroll
    for (int k = 0; k < 2; ++k) {
        int e = tok_e[2*t+k];
        int pos = atomicAdd(&cursors[e], 1);
        int r = pad_off[e] + pos;
        row_token[r] = t;
        row_weight[r] = tok_w[2*t+k];
        token_rows[2*t+k] = r;
    }
}

// ---------- 4: x fp32 -> bf16 ----------
__global__ __launch_bounds__(256) void k_convx(const float* __restrict__ x, u16* __restrict__ xb) {
    size_t i = ((size_t)blockIdx.x * 256 + threadIdx.x) * 8;
    const float4* p = (const float4*)(x + i);
    float4 v0 = p[0], v1 = p[1];
    uint4 o;
    o.x = f2bf(v0.x) | ((unsigned)f2bf(v0.y) << 16);
    o.y = f2bf(v0.z) | ((unsigned)f2bf(v0.w) << 16);
    o.z = f2bf(v1.x) | ((unsigned)f2bf(v1.y) << 16);
    o.w = f2bf(v1.z) | ((unsigned)f2bf(v1.w) << 16);
    *(uint4*)(xb + i) = o;
}

// ---------- 5: weight transpose+convert: [E][R][C] f32 -> [E][C][R] bf16 ----------
template<int R, int C>
__global__ __launch_bounds__(256) void k_transpose(const float* __restrict__ in, u16* __restrict__ out) {
    __shared__ u16 lds[64][260];
    const int TR = R / 256, TC = C / 64;
    const int tiles = TR * TC;
    int e = blockIdx.x / tiles;
    int rem = blockIdx.x % tiles;
    int rt = rem / TC, ct = rem % TC;
    const float* src = in + (size_t)e * R * C + (size_t)rt * 256 * C + ct * 64;
    u16* dst = out + (size_t)e * R * C + (size_t)ct * 64 * R + rt * 256;
    int t = threadIdx.x;
    #pragma unroll
    for (int i = 0; i < 16; ++i) {
        int o = i * 256 + t;
        int r = o >> 4;
        int c4 = (o & 15) * 4;
        float4 v = *(const float4*)&src[(size_t)r * C + c4];
        lds[c4+0][r] = f2bf(v.x);
        lds[c4+1][r] = f2bf(v.y);
        lds[c4+2][r] = f2bf(v.z);
        lds[c4+3][r] = f2bf(v.w);
    }
    __syncthreads();
    #pragma unroll
    for (int i = 0; i < 16; ++i) {
        int o = i * 256 + t;
        int c = o >> 6;
        int r4 = (o & 63) * 4;
        ushort4 u;
        u.x = lds[c][r4+0]; u.y = lds[c][r4+1];
        u.z = lds[c][r4+2]; u.w = lds[c][r4+3];
        *(ushort4*)&dst[(size_t)c * R + r4] = u;
    }
}

// ---------- 6: ring-pipelined MoE GEMM, 32x32x16 MFMA, slot-major LDS ----------
// LDS layout per K-tile slot (BK=32 = 4 k-slots of 8 bf16):
//   byte addr = kslot*(ROWS*16) + row*16  -> fragment reads are contiguous
//   512B runs (conflict-free), global_load_lds dest stays linear, the k-slot
//   permutation rides on the per-lane GLOBAL address.
// Schedule per iter: vmcnt(ahead*L) -> s_barrier -> stage(kt+RING-1) ->
//   compute(kt). Stage-after-barrier makes slot reuse race-free by
//   construction (slot written was last read at kt-1, pre-barrier).
template<int BM, int BN, int WM, int WN, int RING, int N, int K, bool GATHER, bool SILU>
__global__ __launch_bounds__(WM*WN*64, 2) void k_rgemm(
    const u16* __restrict__ Asrc, const u16* __restrict__ Bw,
    const float* __restrict__ bias, void* __restrict__ Out,
    const int* __restrict__ row_token, const int* __restrict__ tile_expert, int mt)
{
    constexpr int TH  = WM * WN * 64;
    constexpr int LA  = 4 * BM / TH;    // gload_lds per thread per K-tile (A)
    constexpr int LB  = 4 * BN / TH;
    constexpr int L   = LA + LB;
    constexpr int NT  = K / 32;
    constexpr int NBN = N / BN;
    constexpr int PWM = BM / WM;        // per-wave output rows
    constexpr int PWN = BN / WN;
    constexpr int FM  = PWM / 32;
    constexpr int FN  = PWN / 32;

    int id = blockIdx.x;
    int cpx = (NBN * mt) >> 3;
    int sid = (id & 7) * cpx + (id >> 3);
    int bm = sid / NBN, bn = sid % NBN;
    int e = tile_expert[bm * (BM / 128)];
    if (e < 0) return;
    int tid = threadIdx.x, wid = tid >> 6, lane = tid & 63;
    int wr = wid / WN, wc = wid % WN;
    int l5 = lane >> 5, l31 = lane & 31;

    __shared__ u16 Asl[RING * BM * 32];
    __shared__ u16 Bsl[RING * BN * 32];

    // staging sources: lds elem idx = l*TH + tid = kslot*ROWS + row
    const char* aptr[LA];
    const char* bptr[LB];
    #pragma unroll
    for (int l = 0; l < LA; ++l) {
        int idx = l * TH + tid;
        int s = idx / BM, row = idx % BM;
        size_t grow;
        if (GATHER) {
            int tk = row_token[bm * BM + row];
            if (tk < 0) tk = 0;            // pad rows: duplicate token 0 (ignored)
            grow = (size_t)tk;
        } else {
            grow = (size_t)(bm * BM + row);
        }
        aptr[l] = (const char*)Asrc + grow * (K * 2) + s * 16;
    }
    #pragma unroll
    for (int l = 0; l < LB; ++l) {
        int idx = l * TH + tid;
        int s = idx / BN, row = idx % BN;
        bptr[l] = (const char*)Bw + ((size_t)e * N + (size_t)(bn * BN + row)) * (K * 2) + s * 16;
    }

    f32x16 acc[FM][FN];
    #pragma unroll
    for (int m = 0; m < FM; ++m)
        #pragma unroll
        for (int n = 0; n < FN; ++n)
            #pragma unroll
            for (int r = 0; r < 16; ++r) acc[m][n][r] = 0.f;

    auto stage = [&](int buf, int kt) {
        unsigned ko = (unsigned)kt * 64u;
        #pragma unroll
        for (int l = 0; l < LA; ++l)
            __builtin_amdgcn_global_load_lds(GLB(aptr[l] + ko),
                LDSP(Asl + buf * (BM * 32) + (l * TH + wid * 64) * 8), 16, 0, 0);
        #pragma unroll
        for (int l = 0; l < LB; ++l)
            __builtin_amdgcn_global_load_lds(GLB(bptr[l] + ko),
                LDSP(Bsl + buf * (BN * 32) + (l * TH + wid * 64) * 8), 16, 0, 0);
    };

    auto compute = [&](int buf) {
        const char* Ab = (const char*)Asl + buf * (BM * 64);
        const char* Bb = (const char*)Bsl + buf * (BN * 64);
        #pragma unroll
        for (int ks = 0; ks < 2; ++ks) {
            int slot = ks * 2 + l5;
            bf16x8 bf[FN];
            #pragma unroll
            for (int n = 0; n < FN; ++n)
                bf[n] = *(const bf16x8*)(Bb + slot * (BN * 16) + (wc * PWN + n * 32 + l31) * 16);
            __builtin_amdgcn_s_setprio(1);
            #pragma unroll
            for (int m = 0; m < FM; ++m) {
                bf16x8 af = *(const bf16x8*)(Ab + slot * (BM * 16) + (wr * PWM + m * 32 + l31) * 16);
                #pragma unroll
                for (int n = 0; n < FN; ++n)
                    acc[m][n] = __builtin_amdgcn_mfma_f32_32x32x16_bf16(af, bf[n], acc[m][n], 0, 0, 0);
            }
            __builtin_amdgcn_s_setprio(0);
        }
    };

    #pragma unroll
    for (int t = 0; t < RING - 1; ++t) stage(t, t);

    int cb = 0;
    for (int kt = 0; kt < NT; ++kt) {
        int ahead = NT - 1 - kt;
        if (ahead > RING - 2) ahead = RING - 2;
        if (ahead >= 2) vmwait<2 * L>();
        else if (ahead == 1) vmwait<L>();
        else vmwait<0>();
        __builtin_amdgcn_s_barrier();
        __builtin_amdgcn_sched_barrier(0);
        int ts = kt + RING - 1;
        if (ts < NT) stage(ts % RING, ts);
        compute(cb);
        __builtin_amdgcn_sched_barrier(0);
        cb = (cb + 1 == RING) ? 0 : cb + 1;
    }

    // epilogue: 32x32 C layout: col = lane&31, row = (r&3) + 8*(r>>2) + 4*(lane>>5)
    #pragma unroll
    for (int n = 0; n < FN; ++n) {
        int col = bn * BN + wc * PWN + n * 32 + l31;
        float bv = bias[e * N + col];
        #pragma unroll
        for (int m = 0; m < FM; ++m) {
            int rbase = bm * BM + wr * PWM + m * 32 + 4 * l5;
            #pragma unroll
            for (int r = 0; r < 16; ++r) {
                int row = rbase + (r & 3) + 8 * (r >> 2);
                float v = acc[m][n][r] + bv;
                if (SILU) {
                    v = v / (1.f + __expf(-v));
                    ((u16*)Out)[(size_t)row * N + col] = f2bf(v);
                } else {
                    ((float*)Out)[(size_t)row * N + col] = v;
                }
            }
        }
    }
}

// ---------- 7: combine (one block per token, float4) ----------
__global__ __launch_bounds__(256) void k_combine(const float* __restrict__ ybuf,
        const int* __restrict__ token_rows, const float* __restrict__ row_weight,
        float* __restrict__ out) {
    int t = blockIdx.x;
    int d = threadIdx.x * 4;
    int r0 = token_rows[2*t], r1 = token_rows[2*t+1];
    float w0 = row_weight[r0], w1 = row_weight[r1];
    const float4 y0 = *(const float4*)&ybuf[(size_t)r0 * DM + d];
    const float4 y1 = *(const float4*)&ybuf[(size_t)r1 * DM + d];
    float4 o;
    o.x = w0*y0.x + w1*y1.x;
    o.y = w0*y0.y + w1*y1.y;
    o.z = w0*y0.z + w1*y1.z;
    o.w = w0*y0.w + w1*y1.w;
    *(float4*)&out[(size_t)t * DM + d] = o;
}

extern "C" void kernel_launch(void* const* d_in, const int* in_sizes, int n_in,
                              void* d_out, int out_size, void* d_ws, size_t ws_size,
                              hipStream_t stream) {
    const float* x  = (const float*)d_in[0];
    const float* gw = (const float*)d_in[1];
    const float* gb = (const float*)d_in[2];
    const float* w1 = (const float*)d_in[3];
    const float* b1 = (const float*)d_in[4];
    const float* w2 = (const float*)d_in[5];
    const float* b2 = (const float*)d_in[6];
    float* out = (float*)d_out;

    char* ws = (char*)d_ws;
    size_t off = 0;
    auto alloc = [&](size_t bytes) -> void* {
        void* p = ws + off; off = (off + bytes + 255) & ~(size_t)255; return p;
    };
    // ybuf (written by GEMM2) aliases w1t+xb, dead after GEMM1 (stream-ordered).
    u16*   w1t  = (u16*)alloc((size_t)NE * DM * HID * 2);   // 67.1 MB
    u16*   xb   = (u16*)alloc((size_t)T_TOK * DM * 2);      // 16.8 MB
    u16*   w2t  = (u16*)alloc((size_t)NE * DM * HID * 2);   // 67.1 MB
    u16*   hbuf = (u16*)alloc((size_t)RP2 * HID * 2);       // 151 MB
    int*   tok_e = (int*)alloc(2 * T_TOK * 4);
    float* tok_w = (float*)alloc(2 * T_TOK * 4);
    int*   counts  = (int*)alloc(64);
    int*   cursors = (int*)alloc(64);
    int*   pad_off = (int*)alloc(64);
    int*   row_token  = (int*)alloc(RP2 * 4);
    float* row_weight = (float*)alloc(RP2 * 4);
    int*   token_rows = (int*)alloc(2 * T_TOK * 4);
    int*   tile_expert = (int*)alloc(MT128 * 4);
    float* ybuf = (float*)w1t;                              // 75.5 MB alias

    k_zero<<<1, 64, 0, stream>>>(counts, cursors);
    k_gate<<<T_TOK/4, 256, 0, stream>>>(x, gw, gb, tok_e, tok_w, counts);
    k_scan<<<1, 256, 0, stream>>>(counts, pad_off, tile_expert, row_token);
    k_assign<<<T_TOK/256, 256, 0, stream>>>(tok_e, tok_w, pad_off, cursors, row_token, row_weight, token_rows);
    k_convx<<<(T_TOK*DM)/(256*8), 256, 0, stream>>>(x, xb);
    k_transpose<DM, HID><<<NE*(DM/256)*(HID/64), 256, 0, stream>>>(w1, w1t);
    k_transpose<HID, DM><<<NE*(HID/256)*(DM/64), 256, 0, stream>>>(w2, w2t);
    // GEMM1: 256x256, 8 waves (2x4, 128x64/wave), ring-4 (128 KiB), K=1024
    k_rgemm<256, 256, 2, 4, 4, HID, DM, true, true><<<(HID/256)*MT256, 512, 0, stream>>>(
        xb, w1t, b1, (void*)hbuf, row_token, tile_expert, MT256);
    // GEMM2: 256x128, 4 waves (2x2, 128x64/wave), ring-3 (72 KiB, 2 blk/CU), K=4096
    k_rgemm<256, 128, 2, 2, 3, DM, HID, false, false><<<(DM/128)*MT256, 256, 0, stream>>>(
        hbuf, w2t, b2, (void*)ybuf, row_token, tile_expert, MT256);
    k_combine<<<T_TOK, 256, 0, stream>>>(ybuf, token_rows, row_weight, out);
}